// Round 3
// baseline (288.726 us; speedup 1.0000x reference)
//
#include <hip/hip_runtime.h>

// GraphConv: out = relu( D * A_hat * D * x * W ),  B=8, N=2048, F=O=128, fp32.
// Factored:  out[n,o] = relu( sum_m (d[n]*A_hat[n,m]) * (d[m]*(xW)[m,o]) )
// K0: Wt[o][f] = bf16(W^T)                          (32 KB)
// K1: per row: d=1/(eps+sqrt(rowsum A_hat));  adjb[n][m]=bf16(d[n]*A_hat)   (row-prescaled, diag fixed)
// K2: yt[b][o][m] = bf16(d[m]*(x@W)[m,o])           (LDS-free MFMA, K=128)
// K3: out = relu(adjb @ yt^T)                       (LDS-free MFMA, K=2048)
//
// R3: no LDS anywhere. MFMA fragments load straight from global:
//  - A-frag (k-contiguous bf16) = one global_load_dwordx4
//  - B-frag from yt: L2-resident per XCD (batch = blockIdx.x & 7 swizzle)
// No barriers, no staging VALU in the hot loop; unroll-4 lets the compiler
// keep ~20 vmem loads in flight per wave.

typedef __bf16 bf16x8 __attribute__((ext_vector_type(8)));
typedef __bf16 bf16x4 __attribute__((ext_vector_type(4)));
typedef float  f32x4  __attribute__((ext_vector_type(4)));

#define NN 2048
#define NB 8

// ---------------- K0: W [128][128] fp32 -> Wt [o][f] bf16 ----------------
__global__ __launch_bounds__(256) void wt_kernel(const float* __restrict__ W,
                                                 __bf16* __restrict__ Wt) {
    int idx = blockIdx.x * 256 + threadIdx.x;   // grid 64
    int f = idx >> 7, o = idx & 127;
    Wt[o * 128 + f] = (__bf16)W[idx];
}

// ---------------- K1: rowsum -> d; write bf16 row-prescaled A_hat --------
__global__ __launch_bounds__(256) void prep_kernel(const float* __restrict__ adj,
                                                   float* __restrict__ dvec,
                                                   __bf16* __restrict__ adjb) {
    const int lane = threadIdx.x & 63;
    const int row  = blockIdx.x * 4 + (threadIdx.x >> 6);   // one wave per row
    const float* rp = adj + (size_t)row * NN;
    __bf16* wp = adjb + (size_t)row * NN;
    const int n = row & (NN - 1);           // diagonal column index

    f32x4 v[8];
    float s = 0.f;
#pragma unroll
    for (int it = 0; it < 8; ++it) {
        v[it] = *(const f32x4*)(rp + it * 256 + lane * 4);
        s += (v[it].x + v[it].y) + (v[it].z + v[it].w);
    }
#pragma unroll
    for (int off = 1; off < 64; off <<= 1) s += __shfl_xor(s, off);
    float diag = rp[n];                     // same addr all lanes -> broadcast
    float d = 1.0f / (1e-6f + sqrtf(s - diag + 1.0f));
    if (lane == 0) dvec[row] = d;

#pragma unroll
    for (int it = 0; it < 8; ++it) {
        int c0 = it * 256 + lane * 4;
        float f0 = (c0     == n) ? 1.0f : v[it].x;
        float f1 = (c0 + 1 == n) ? 1.0f : v[it].y;
        float f2 = (c0 + 2 == n) ? 1.0f : v[it].z;
        float f3 = (c0 + 3 == n) ? 1.0f : v[it].w;
        bf16x4 o4;
        o4[0] = (__bf16)(f0 * d); o4[1] = (__bf16)(f1 * d);
        o4[2] = (__bf16)(f2 * d); o4[3] = (__bf16)(f3 * d);
        *(bf16x4*)(wp + c0) = o4;
    }
}

// ---------------- K2: yt[b][o][m] = bf16(d[m] * (x@W)[m,o]), LDS-free ----
// Wave: 16 m-rows x 128 o.  grid 256 blocks (4 waves), b = blockIdx.x & 7.
__global__ __launch_bounds__(256) void xw_kernel(const float* __restrict__ x,
                                                 const __bf16* __restrict__ Wt,
                                                 const float* __restrict__ dvec,
                                                 __bf16* __restrict__ yt) {
    const int lane = threadIdx.x & 63;
    const int wave = threadIdx.x >> 6;
    const int b    = blockIdx.x & 7;
    const int mt   = (blockIdx.x >> 3) * 4 + wave;   // 0..127
    const int m0   = mt * 16;
    const int kgrp = (lane >> 4) * 8;
    const float* xp = x + ((size_t)b * NN + m0 + (lane & 15)) * 128 + kgrp;

    f32x4 acc[8];
#pragma unroll
    for (int i = 0; i < 8; ++i) acc[i] = (f32x4){0.f, 0.f, 0.f, 0.f};

#pragma unroll
    for (int kt = 0; kt < 4; ++kt) {
        f32x4 a0 = *(const f32x4*)(xp + kt * 32);
        f32x4 a1 = *(const f32x4*)(xp + kt * 32 + 4);
        float av[8] = {a0.x, a0.y, a0.z, a0.w, a1.x, a1.y, a1.z, a1.w};
        bf16x8 af;
#pragma unroll
        for (int j = 0; j < 8; ++j) af[j] = (__bf16)av[j];
#pragma unroll
        for (int nb = 0; nb < 8; ++nb) {
            bf16x8 bfv = *(const bf16x8*)(Wt + (nb * 16 + (lane & 15)) * 128 +
                                          kt * 32 + kgrp);
            acc[nb] = __builtin_amdgcn_mfma_f32_16x16x32_bf16(af, bfv, acc[nb], 0, 0, 0);
        }
    }
    // epilogue: C/D col=lane&15, row=(lane>>4)*4+r ; scale by d[m]
    const int col0 = lane & 15;
    const int rq   = (lane >> 4) * 4;
#pragma unroll
    for (int r = 0; r < 4; ++r) {
        int m = m0 + rq + r;
        float dm = dvec[b * NN + m];
#pragma unroll
        for (int nb = 0; nb < 8; ++nb) {
            int o = nb * 16 + col0;
            yt[((size_t)b * 128 + o) * NN + m] = (__bf16)(acc[nb][r] * dm);
        }
    }
}

// ---------------- K3: out = relu(adjb @ yt^T), LDS-free ------------------
// Wave: 16 n-rows x 64 o-cols. Block: 4 waves = 32 rows x 128 cols.
// grid 512 (2 blocks/CU), b = blockIdx.x & 7 (XCD-aligned with yt slice).
__global__ __launch_bounds__(256) void gemm_kernel(const __bf16* __restrict__ adjb,
                                                   const __bf16* __restrict__ yt,
                                                   float* __restrict__ out) {
    const int lane = threadIdx.x & 63;
    const int wave = threadIdx.x >> 6;
    const int b    = blockIdx.x & 7;
    const int tile = blockIdx.x >> 3;            // 0..63
    const int rsel = (wave & 1) * 16;
    const int csel = (wave >> 1) * 64;
    const int kgrp = (lane >> 4) * 8;

    const __bf16* ap =
        adjb + ((size_t)b * NN + tile * 32 + rsel + (lane & 15)) * NN + kgrp;
    const __bf16* bbase = yt + (size_t)b * 128 * NN + kgrp;
    const __bf16* bp0 = bbase + (size_t)(csel + 0 * 16 + (lane & 15)) * NN;
    const __bf16* bp1 = bbase + (size_t)(csel + 1 * 16 + (lane & 15)) * NN;
    const __bf16* bp2 = bbase + (size_t)(csel + 2 * 16 + (lane & 15)) * NN;
    const __bf16* bp3 = bbase + (size_t)(csel + 3 * 16 + (lane & 15)) * NN;

    f32x4 acc[4];
#pragma unroll
    for (int i = 0; i < 4; ++i) acc[i] = (f32x4){0.f, 0.f, 0.f, 0.f};

#pragma unroll 4
    for (int kt = 0; kt < 64; ++kt) {
        const int ko = kt * 32;
        bf16x8 af  = *(const bf16x8*)(ap  + ko);
        bf16x8 bf0 = *(const bf16x8*)(bp0 + ko);
        bf16x8 bf1 = *(const bf16x8*)(bp1 + ko);
        bf16x8 bf2 = *(const bf16x8*)(bp2 + ko);
        bf16x8 bf3 = *(const bf16x8*)(bp3 + ko);
        acc[0] = __builtin_amdgcn_mfma_f32_16x16x32_bf16(af, bf0, acc[0], 0, 0, 0);
        acc[1] = __builtin_amdgcn_mfma_f32_16x16x32_bf16(af, bf1, acc[1], 0, 0, 0);
        acc[2] = __builtin_amdgcn_mfma_f32_16x16x32_bf16(af, bf2, acc[2], 0, 0, 0);
        acc[3] = __builtin_amdgcn_mfma_f32_16x16x32_bf16(af, bf3, acc[3], 0, 0, 0);
    }

    // epilogue: relu, coalesced fp32 stores (16 consecutive o per lane group)
    const int col0 = lane & 15;
    const int rq   = (lane >> 4) * 4;
    float* op = out + ((size_t)b * NN + tile * 32 + rsel) * 128;
#pragma unroll
    for (int r = 0; r < 4; ++r) {
#pragma unroll
        for (int nb = 0; nb < 4; ++nb) {
            float v = acc[nb][r];
            op[(rq + r) * 128 + csel + nb * 16 + col0] = v > 0.f ? v : 0.f;
        }
    }
}

extern "C" void kernel_launch(void* const* d_in, const int* in_sizes, int n_in,
                              void* d_out, int out_size, void* d_ws, size_t ws_size,
                              hipStream_t stream) {
    const float* x   = (const float*)d_in[0];   // [8,2048,128]
    const float* adj = (const float*)d_in[1];   // [8,2048,2048]
    const float* W   = (const float*)d_in[2];   // [128,128]
    float* out = (float*)d_out;

    char* ws = (char*)d_ws;
    float*  dvec = (float*)ws;                          // 64 KB
    __bf16* Wt   = (__bf16*)(ws + (64 << 10));          // 32 KB
    __bf16* yt   = (__bf16*)(ws + (128 << 10));         // 4 MB   [B][128][2048]
    __bf16* adjb = (__bf16*)(ws + (128 << 10) + ((size_t)NB * 128 * NN * 2)); // 64 MB

    hipLaunchKernelGGL(wt_kernel, dim3(64), dim3(256), 0, stream, W, Wt);
    hipLaunchKernelGGL(prep_kernel, dim3(NB * NN / 4), dim3(256), 0, stream,
                       adj, dvec, adjb);
    hipLaunchKernelGGL(xw_kernel, dim3(256), dim3(256), 0, stream,
                       x, Wt, dvec, yt);
    hipLaunchKernelGGL(gemm_kernel, dim3(512), dim3(256), 0, stream,
                       adjb, yt, out);
}

// Round 4
// 248.226 us; speedup vs baseline: 1.1632x; 1.1632x over previous
//
#include <hip/hip_runtime.h>

// GraphConv: out = relu( D * A_hat * D * x * W ),  B=8, N=2048, F=O=128, fp32.
// Factored:  out[n,o] = relu( d[n] * sum_m A_hat[n,m] * (d[m]*(xW)[m,o]) )
// K0: Wt[o][f] = bf16(W^T)
// K1: d = 1/(eps+sqrt(rowsum(A_hat)))      (one 134 MB pass over adj)
// K2: yt[b][o][m] = bf16(d[m]*(x@W)[m,o])  (LDS-free MFMA, K=128)
// K3: out = relu(d[n]*(adj_raw @ yt^T + (1-adj[n,n])*yt[:,n]))  (K=2048)
//
// R4: K3 loads A-fragments DIRECTLY from fp32 adj (k-contiguous, 2x dwordx4
// per lane per iter), converts in-reg; diagonal fixed by exact epilogue
// post-correction (GEMM runs on raw adj). B stays on the proven dbuf
// global_load_lds pipeline, 1 barrier/iter, 2 blocks/CU.

typedef __bf16 bf16x8 __attribute__((ext_vector_type(8)));
typedef __bf16 bf16x4 __attribute__((ext_vector_type(4)));
typedef float  f32x4  __attribute__((ext_vector_type(4)));

#define NN 2048
#define NB 8

__device__ __forceinline__ void load_lds16(__bf16* lds, const __bf16* g) {
    // per-lane global src; LDS dest = wave-uniform base + lane*16
    __builtin_amdgcn_global_load_lds(
        (const __attribute__((address_space(1))) void*)g,
        (__attribute__((address_space(3))) void*)lds, 16, 0, 0);
}

// ---------------- K0: W [128][128] fp32 -> Wt [o][f] bf16 ----------------
__global__ __launch_bounds__(256) void wt_kernel(const float* __restrict__ W,
                                                 __bf16* __restrict__ Wt) {
    int idx = blockIdx.x * 256 + threadIdx.x;   // grid 64
    int f = idx >> 7, o = idx & 127;
    Wt[o * 128 + f] = (__bf16)W[idx];
}

// ---------------- K1: degree vector (pure rowsum pass) -------------------
__global__ __launch_bounds__(256) void d_kernel(const float* __restrict__ adj,
                                                float* __restrict__ dvec) {
    const int lane = threadIdx.x & 63;
    const int row  = blockIdx.x * 4 + (threadIdx.x >> 6);   // one wave per row
    const float* rp = adj + (size_t)row * NN;
    float4 s4 = {0.f, 0.f, 0.f, 0.f};
#pragma unroll
    for (int it = 0; it < 8; ++it) {
        float4 v = *(const float4*)(rp + it * 256 + lane * 4);
        s4.x += v.x; s4.y += v.y; s4.z += v.z; s4.w += v.w;
    }
    float s = (s4.x + s4.y) + (s4.z + s4.w);
#pragma unroll
    for (int off = 32; off; off >>= 1) s += __shfl_down(s, off);
    if (lane == 0) {
        int n = row & (NN - 1);
        float sh = s - rp[n] + 1.0f;            // zero diag, add self-loop
        dvec[row] = 1.0f / (1e-6f + sqrtf(sh));
    }
}

// ---------------- K2: yt[b][o][m] = bf16(d[m] * (x@W)[m,o]), LDS-free ----
__global__ __launch_bounds__(256) void xw_kernel(const float* __restrict__ x,
                                                 const __bf16* __restrict__ Wt,
                                                 const float* __restrict__ dvec,
                                                 __bf16* __restrict__ yt) {
    const int lane = threadIdx.x & 63;
    const int wave = threadIdx.x >> 6;
    const int b    = blockIdx.x & 7;
    const int mt   = (blockIdx.x >> 3) * 4 + wave;   // 0..127
    const int m0   = mt * 16;
    const int kgrp = (lane >> 4) * 8;
    const float* xp = x + ((size_t)b * NN + m0 + (lane & 15)) * 128 + kgrp;

    f32x4 acc[8];
#pragma unroll
    for (int i = 0; i < 8; ++i) acc[i] = (f32x4){0.f, 0.f, 0.f, 0.f};

#pragma unroll
    for (int kt = 0; kt < 4; ++kt) {
        f32x4 a0 = *(const f32x4*)(xp + kt * 32);
        f32x4 a1 = *(const f32x4*)(xp + kt * 32 + 4);
        float av[8] = {a0.x, a0.y, a0.z, a0.w, a1.x, a1.y, a1.z, a1.w};
        bf16x8 af;
#pragma unroll
        for (int j = 0; j < 8; ++j) af[j] = (__bf16)av[j];
#pragma unroll
        for (int nb = 0; nb < 8; ++nb) {
            bf16x8 bfv = *(const bf16x8*)(Wt + (nb * 16 + (lane & 15)) * 128 +
                                          kt * 32 + kgrp);
            acc[nb] = __builtin_amdgcn_mfma_f32_16x16x32_bf16(af, bfv, acc[nb], 0, 0, 0);
        }
    }
    const int col0 = lane & 15;
    const int rq   = (lane >> 4) * 4;
#pragma unroll
    for (int r = 0; r < 4; ++r) {
        int m = m0 + rq + r;
        float dm = dvec[b * NN + m];
#pragma unroll
        for (int nb = 0; nb < 8; ++nb) {
            int o = nb * 16 + col0;
            yt[((size_t)b * 128 + o) * NN + m] = (__bf16)(acc[nb][r] * dm);
        }
    }
}

// ---------------- K3: direct-A GEMM with epilogue diag correction --------
// Block 256 thr: 32 rows x 128 cols; wave w: rows (w&1)*16, cols (w>>1)*64.
// grid 512 (2 blocks/CU), b = blockIdx.x & 7.
__global__ __launch_bounds__(256) void gemm_kernel(const float* __restrict__ adj,
                                                   const __bf16* __restrict__ yt,
                                                   const float* __restrict__ dvec,
                                                   float* __restrict__ out) {
    __shared__ alignas(16) __bf16 sB[2][128][32];

    const int tid  = threadIdx.x;
    const int wave = tid >> 6;
    const int lane = tid & 63;
    const int b    = blockIdx.x & 7;
    const int tile = blockIdx.x >> 3;            // 0..63
    const int rsel = (wave & 1) * 16;
    const int csel = (wave >> 1) * 64;
    const int kgrp = (lane >> 4) * 8;

    // A: direct from global fp32, k-contiguous fragment
    const int arow_loc = tile * 32 + rsel + (lane & 15);
    const float* ap = adj + ((size_t)b * NN + arow_loc) * NN + kgrp;

    const __bf16* ytb = yt + (size_t)b * 128 * NN;
    const int b_row0 = wave * 32;
    const __bf16* b_src = ytb + (size_t)(b_row0 + (lane >> 2)) * NN + (lane & 3) * 8;

    f32x4 acc[4];
#pragma unroll
    for (int i = 0; i < 4; ++i) acc[i] = (f32x4){0.f, 0.f, 0.f, 0.f};

    // preload iter 0
    load_lds16(&sB[0][b_row0][0], b_src);
    load_lds16(&sB[0][b_row0 + 16][0], b_src + (size_t)16 * NN);
    f32x4 ca0 = *(const f32x4*)(ap);
    f32x4 ca1 = *(const f32x4*)(ap + 4);

    for (int kt = 0; kt < 64; ++kt) {
        const int cur = kt & 1;
        __syncthreads();   // drains loads issued last iter (glds + A regs)

        // issue NEXT iter's loads first: in flight through the MFMA phase
        f32x4 na0, na1;
        if (kt + 1 < 64) {
            const __bf16* bs = b_src + (size_t)(kt + 1) * 32;
            load_lds16(&sB[cur ^ 1][b_row0][0], bs);
            load_lds16(&sB[cur ^ 1][b_row0 + 16][0], bs + (size_t)16 * NN);
            na0 = *(const f32x4*)(ap + (kt + 1) * 32);
            na1 = *(const f32x4*)(ap + (kt + 1) * 32 + 4);
        }

        // convert current A regs (loaded last iter, drained by the barrier)
        bf16x8 af;
        af[0] = (__bf16)ca0.x; af[1] = (__bf16)ca0.y;
        af[2] = (__bf16)ca0.z; af[3] = (__bf16)ca0.w;
        af[4] = (__bf16)ca1.x; af[5] = (__bf16)ca1.y;
        af[6] = (__bf16)ca1.z; af[7] = (__bf16)ca1.w;

#pragma unroll
        for (int nb = 0; nb < 4; ++nb) {
            bf16x8 bfv = *(const bf16x8*)(
                &sB[cur][csel + nb * 16 + (lane & 15)][kgrp]);
            acc[nb] = __builtin_amdgcn_mfma_f32_16x16x32_bf16(af, bfv, acc[nb], 0, 0, 0);
        }
        ca0 = na0; ca1 = na1;
    }

    // epilogue: diag correction + row scale + relu
    // acc = sum_m bf16(adj_raw[n,m]) * yt[o][m]; want diag term 1*yt[o][n]:
    //   out = d[n] * (acc + (1 - adj[n,n]) * yt[o][n])
    const int col0 = lane & 15;
    const int rq   = (lane >> 4) * 4;
#pragma unroll
    for (int r = 0; r < 4; ++r) {
        int n_loc = tile * 32 + rsel + rq + r;
        size_t grow = (size_t)b * NN + n_loc;
        float dn   = dvec[grow];
        float cfac = 1.0f - adj[grow * NN + n_loc];
#pragma unroll
        for (int nb = 0; nb < 4; ++nb) {
            int o = csel + nb * 16 + col0;
            float yp = (float)ytb[(size_t)o * NN + n_loc];
            float v = (acc[nb][r] + cfac * yp) * dn;
            out[grow * 128 + o] = v > 0.f ? v : 0.f;
        }
    }
}

extern "C" void kernel_launch(void* const* d_in, const int* in_sizes, int n_in,
                              void* d_out, int out_size, void* d_ws, size_t ws_size,
                              hipStream_t stream) {
    const float* x   = (const float*)d_in[0];   // [8,2048,128]
    const float* adj = (const float*)d_in[1];   // [8,2048,2048]
    const float* W   = (const float*)d_in[2];   // [128,128]
    float* out = (float*)d_out;

    char* ws = (char*)d_ws;
    float*  dvec = (float*)ws;                          // 64 KB
    __bf16* Wt   = (__bf16*)(ws + (64 << 10));          // 32 KB
    __bf16* yt   = (__bf16*)(ws + (128 << 10));         // 4 MB  [B][128][2048]

    hipLaunchKernelGGL(wt_kernel, dim3(64), dim3(256), 0, stream, W, Wt);
    hipLaunchKernelGGL(d_kernel, dim3(NB * NN / 4), dim3(256), 0, stream, adj, dvec);
    hipLaunchKernelGGL(xw_kernel, dim3(256), dim3(256), 0, stream, x, Wt, dvec, yt);
    hipLaunchKernelGGL(gemm_kernel, dim3(512), dim3(256), 0, stream,
                       adj, yt, dvec, out);
}

// Round 5
// 244.795 us; speedup vs baseline: 1.1795x; 1.0140x over previous
//
#include <hip/hip_runtime.h>

// GraphConv: out = relu( D * A_hat * D * x * W ),  B=8, N=2048, F=O=128, fp32.
// Factored:  out[n,o] = relu( d[n] * sum_m A_hat[n,m] * (d[m]*(xW)[m,o]) )
// K1: d = 1/(eps+sqrt(rowsum(A_hat)))  + tail blocks convert Wt=bf16(W^T)
// K2: yt[b][o][m] = bf16(d[m]*(x@W)[m,o])  (LDS-free MFMA, K=128)
// K3: out = relu(d[n]*(adj_raw @ yt^T + (1-adj[n,n])*yt[:,n]))  (K=2048)
//
// R5: consolidation — K0 folded into K1's grid (64 tail blocks), 3 launches.
// K3 unchanged from R4 (direct fp32 A-frag loads + dbuf global_load_lds B,
// 1 barrier/iter): proven memory-bound at the 134 MB/pass floor.

typedef __bf16 bf16x8 __attribute__((ext_vector_type(8)));
typedef __bf16 bf16x4 __attribute__((ext_vector_type(4)));
typedef float  f32x4  __attribute__((ext_vector_type(4)));

#define NN 2048
#define NB 8

__device__ __forceinline__ void load_lds16(__bf16* lds, const __bf16* g) {
    // per-lane global src; LDS dest = wave-uniform base + lane*16
    __builtin_amdgcn_global_load_lds(
        (const __attribute__((address_space(1))) void*)g,
        (__attribute__((address_space(3))) void*)lds, 16, 0, 0);
}

// ---------------- K1: degree vector + Wt convert in tail blocks ----------
__global__ __launch_bounds__(256) void d_kernel(const float* __restrict__ adj,
                                                float* __restrict__ dvec,
                                                const float* __restrict__ W,
                                                __bf16* __restrict__ Wt) {
    if (blockIdx.x >= NB * NN / 4) {
        // tail: Wt[o][f] = bf16(W[f][o]),  64 blocks x 256 thr = 16384
        int idx = (blockIdx.x - NB * NN / 4) * 256 + threadIdx.x;
        int f = idx >> 7, o = idx & 127;
        Wt[o * 128 + f] = (__bf16)W[idx];
        return;
    }
    const int lane = threadIdx.x & 63;
    const int row  = blockIdx.x * 4 + (threadIdx.x >> 6);   // one wave per row
    const float* rp = adj + (size_t)row * NN;
    float4 s4 = {0.f, 0.f, 0.f, 0.f};
#pragma unroll
    for (int it = 0; it < 8; ++it) {
        float4 v = *(const float4*)(rp + it * 256 + lane * 4);
        s4.x += v.x; s4.y += v.y; s4.z += v.z; s4.w += v.w;
    }
    float s = (s4.x + s4.y) + (s4.z + s4.w);
#pragma unroll
    for (int off = 32; off; off >>= 1) s += __shfl_down(s, off);
    if (lane == 0) {
        int n = row & (NN - 1);
        float sh = s - rp[n] + 1.0f;            // zero diag, add self-loop
        dvec[row] = 1.0f / (1e-6f + sqrtf(sh));
    }
}

// ---------------- K2: yt[b][o][m] = bf16(d[m] * (x@W)[m,o]), LDS-free ----
__global__ __launch_bounds__(256) void xw_kernel(const float* __restrict__ x,
                                                 const __bf16* __restrict__ Wt,
                                                 const float* __restrict__ dvec,
                                                 __bf16* __restrict__ yt) {
    const int lane = threadIdx.x & 63;
    const int wave = threadIdx.x >> 6;
    const int b    = blockIdx.x & 7;
    const int mt   = (blockIdx.x >> 3) * 4 + wave;   // 0..127
    const int m0   = mt * 16;
    const int kgrp = (lane >> 4) * 8;
    const float* xp = x + ((size_t)b * NN + m0 + (lane & 15)) * 128 + kgrp;

    f32x4 acc[8];
#pragma unroll
    for (int i = 0; i < 8; ++i) acc[i] = (f32x4){0.f, 0.f, 0.f, 0.f};

#pragma unroll
    for (int kt = 0; kt < 4; ++kt) {
        f32x4 a0 = *(const f32x4*)(xp + kt * 32);
        f32x4 a1 = *(const f32x4*)(xp + kt * 32 + 4);
        float av[8] = {a0.x, a0.y, a0.z, a0.w, a1.x, a1.y, a1.z, a1.w};
        bf16x8 af;
#pragma unroll
        for (int j = 0; j < 8; ++j) af[j] = (__bf16)av[j];
#pragma unroll
        for (int nb = 0; nb < 8; ++nb) {
            bf16x8 bfv = *(const bf16x8*)(Wt + (nb * 16 + (lane & 15)) * 128 +
                                          kt * 32 + kgrp);
            acc[nb] = __builtin_amdgcn_mfma_f32_16x16x32_bf16(af, bfv, acc[nb], 0, 0, 0);
        }
    }
    const int col0 = lane & 15;
    const int rq   = (lane >> 4) * 4;
#pragma unroll
    for (int r = 0; r < 4; ++r) {
        int m = m0 + rq + r;
        float dm = dvec[b * NN + m];
#pragma unroll
        for (int nb = 0; nb < 8; ++nb) {
            int o = nb * 16 + col0;
            yt[((size_t)b * 128 + o) * NN + m] = (__bf16)(acc[nb][r] * dm);
        }
    }
}

// ---------------- K3: direct-A GEMM with epilogue diag correction --------
// Block 256 thr: 32 rows x 128 cols; wave w: rows (w&1)*16, cols (w>>1)*64.
// grid 512 (2 blocks/CU), b = blockIdx.x & 7.
__global__ __launch_bounds__(256) void gemm_kernel(const float* __restrict__ adj,
                                                   const __bf16* __restrict__ yt,
                                                   const float* __restrict__ dvec,
                                                   float* __restrict__ out) {
    __shared__ alignas(16) __bf16 sB[2][128][32];

    const int tid  = threadIdx.x;
    const int wave = tid >> 6;
    const int lane = tid & 63;
    const int b    = blockIdx.x & 7;
    const int tile = blockIdx.x >> 3;            // 0..63
    const int rsel = (wave & 1) * 16;
    const int csel = (wave >> 1) * 64;
    const int kgrp = (lane >> 4) * 8;

    // A: direct from global fp32, k-contiguous fragment
    const int arow_loc = tile * 32 + rsel + (lane & 15);
    const float* ap = adj + ((size_t)b * NN + arow_loc) * NN + kgrp;

    const __bf16* ytb = yt + (size_t)b * 128 * NN;
    const int b_row0 = wave * 32;
    const __bf16* b_src = ytb + (size_t)(b_row0 + (lane >> 2)) * NN + (lane & 3) * 8;

    f32x4 acc[4];
#pragma unroll
    for (int i = 0; i < 4; ++i) acc[i] = (f32x4){0.f, 0.f, 0.f, 0.f};

    // preload iter 0
    load_lds16(&sB[0][b_row0][0], b_src);
    load_lds16(&sB[0][b_row0 + 16][0], b_src + (size_t)16 * NN);
    f32x4 ca0 = *(const f32x4*)(ap);
    f32x4 ca1 = *(const f32x4*)(ap + 4);

    for (int kt = 0; kt < 64; ++kt) {
        const int cur = kt & 1;
        __syncthreads();   // drains loads issued last iter (glds + A regs)

        // issue NEXT iter's loads first: in flight through the MFMA phase
        f32x4 na0, na1;
        if (kt + 1 < 64) {
            const __bf16* bs = b_src + (size_t)(kt + 1) * 32;
            load_lds16(&sB[cur ^ 1][b_row0][0], bs);
            load_lds16(&sB[cur ^ 1][b_row0 + 16][0], bs + (size_t)16 * NN);
            na0 = *(const f32x4*)(ap + (kt + 1) * 32);
            na1 = *(const f32x4*)(ap + (kt + 1) * 32 + 4);
        }

        // convert current A regs (loaded last iter, drained by the barrier)
        bf16x8 af;
        af[0] = (__bf16)ca0.x; af[1] = (__bf16)ca0.y;
        af[2] = (__bf16)ca0.z; af[3] = (__bf16)ca0.w;
        af[4] = (__bf16)ca1.x; af[5] = (__bf16)ca1.y;
        af[6] = (__bf16)ca1.z; af[7] = (__bf16)ca1.w;

#pragma unroll
        for (int nb = 0; nb < 4; ++nb) {
            bf16x8 bfv = *(const bf16x8*)(
                &sB[cur][csel + nb * 16 + (lane & 15)][kgrp]);
            acc[nb] = __builtin_amdgcn_mfma_f32_16x16x32_bf16(af, bfv, acc[nb], 0, 0, 0);
        }
        ca0 = na0; ca1 = na1;
    }

    // epilogue: diag correction + row scale + relu
    //   out = d[n] * (acc + (1 - adj[n,n]) * yt[o][n])
    const int col0 = lane & 15;
    const int rq   = (lane >> 4) * 4;
#pragma unroll
    for (int r = 0; r < 4; ++r) {
        int n_loc = tile * 32 + rsel + rq + r;
        size_t grow = (size_t)b * NN + n_loc;
        float dn   = dvec[grow];
        float cfac = 1.0f - adj[grow * NN + n_loc];
#pragma unroll
        for (int nb = 0; nb < 4; ++nb) {
            int o = csel + nb * 16 + col0;
            float yp = (float)ytb[(size_t)o * NN + n_loc];
            float v = (acc[nb][r] + cfac * yp) * dn;
            out[grow * 128 + o] = v > 0.f ? v : 0.f;
        }
    }
}

extern "C" void kernel_launch(void* const* d_in, const int* in_sizes, int n_in,
                              void* d_out, int out_size, void* d_ws, size_t ws_size,
                              hipStream_t stream) {
    const float* x   = (const float*)d_in[0];   // [8,2048,128]
    const float* adj = (const float*)d_in[1];   // [8,2048,2048]
    const float* W   = (const float*)d_in[2];   // [128,128]
    float* out = (float*)d_out;

    char* ws = (char*)d_ws;
    float*  dvec = (float*)ws;                          // 64 KB
    __bf16* Wt   = (__bf16*)(ws + (64 << 10));          // 32 KB
    __bf16* yt   = (__bf16*)(ws + (128 << 10));         // 4 MB  [B][128][2048]

    hipLaunchKernelGGL(d_kernel, dim3(NB * NN / 4 + 64), dim3(256), 0, stream,
                       adj, dvec, W, Wt);
    hipLaunchKernelGGL(xw_kernel, dim3(256), dim3(256), 0, stream, x, Wt, dvec, yt);
    hipLaunchKernelGGL(gemm_kernel, dim3(512), dim3(256), 0, stream,
                       adj, yt, dvec, out);
}